// Round 7
// baseline (197.963 us; speedup 1.0000x reference)
//
#include <hip/hip_runtime.h>

typedef __attribute__((ext_vector_type(8))) short short8;
typedef __attribute__((ext_vector_type(4))) float f32x4;

#define N_ATOMS 4096
#define N_NEIGH 32
#define IN_F 128
#define HID 256
#define OUT_F 128
#define N_SPECIES 64

// RNE round to bf16 (weights: 2-term split keeps only wh).
__device__ __forceinline__ unsigned short f2bf(float f) {
  unsigned u = __float_as_uint(f);
  u += 0x7FFF + ((u >> 16) & 1);
  return (unsigned short)(u >> 16);
}
// Truncation hi/lo split for activations (hi exact chop, lo exact residual).
struct HL { short h, l; };
__device__ __forceinline__ HL split2(float v) {
  unsigned u = __float_as_uint(v);
  float lo = v - __uint_as_float(u & 0xFFFF0000u);
  HL o;
  o.h = (short)(u >> 16);
  o.l = (short)(__float_as_uint(lo) >> 16);
  return o;
}

// ---------- kernel 1: (block 0) counting sort | (blocks 1..) W -> bf16 RNE ----------
__global__ __launch_bounds__(256) void prep_kernel(
    const float* __restrict__ W1, const float* __restrict__ W2,
    const int* __restrict__ sp_idx,
    unsigned short* __restrict__ w1h, unsigned short* __restrict__ w2h,
    int* __restrict__ atom_order, int* __restrict__ sp_off, int* __restrict__ sp_cnt) {
  const int t = threadIdx.x;
  if (blockIdx.x == 0) {
    __shared__ int cnt[N_SPECIES], off[N_SPECIES], cur[N_SPECIES];
    if (t < N_SPECIES) cnt[t] = 0;
    __syncthreads();
    for (int a = t; a < N_ATOMS; a += 256) atomicAdd(&cnt[sp_idx[a]], 1);
    __syncthreads();
    if (t == 0) {
      int o = 0;
      for (int s = 0; s < N_SPECIES; ++s) { off[s] = o; cur[s] = o; o += cnt[s]; }
    }
    __syncthreads();
    for (int a = t; a < N_ATOMS; a += 256) {
      int s = sp_idx[a];
      atom_order[atomicAdd(&cur[s], 1)] = a;
    }
    if (t < N_SPECIES) { sp_off[t] = off[t]; sp_cnt[t] = cnt[t]; }
    return;
  }
  const int NV = (N_SPECIES * HID * IN_F) / 4;  // float4 count per matrix
  const int nsplit = (gridDim.x - 1) * 256;
  for (int v = (blockIdx.x - 1) * 256 + t; v < 2 * NV; v += nsplit) {
    const float4* src; unsigned short* dh; int j;
    if (v < NV) { src = (const float4*)W1; dh = w1h; j = v; }
    else        { src = (const float4*)W2; dh = w2h; j = v - NV; }
    float4 f = src[j];
    ushort4 h;
    h.x = f2bf(f.x); h.y = f2bf(f.y); h.z = f2bf(f.z); h.w = f2bf(f.w);
    ((ushort4*)dh)[j] = h;
  }
}

// ---------- kernel 2: persistent species-partition MLP ----------
// Grid = 256 blocks = (64 species x 4 quarters), 1 block/CU (160 KB LDS).
// Block stages its species' W1h/W2h ONCE, then each of its 8 waves free-runs
// over ~2 atoms sequentially with register-level feature prefetch (next atom's
// raw f32 loads issued before current atom's compute). One barrier total.
// LDS: W1h 64 KB (^(h&7)<<4) + W2h 64 KB (^(o&7)<<4) + 8 x 4 KB lx
//      (byte = n*128 + ((h*4)^((n&7)<<4)), <=2-way on write and b128 read).
__global__ __launch_bounds__(512, 2) void mlp_kernel(
    const float* __restrict__ feat,
    const float* __restrict__ b1g, const float* __restrict__ b2g,
    const unsigned short* __restrict__ w1h, const unsigned short* __restrict__ w2h,
    const int* __restrict__ atom_order, const int* __restrict__ sp_off,
    const int* __restrict__ sp_cnt,
    float* __restrict__ out) {
  extern __shared__ char smem[];
  char* LW1 = smem;            // 64 KB
  char* LW2 = smem + 65536;    // 64 KB

  const int bid = blockIdx.x;
  // same species -> same (bid&7) -> same XCD (round-robin dispatch heuristic)
  const int s = (bid & 7) * 8 + (bid >> 5);
  const int p = (bid >> 3) & 3;
  const int tid = threadIdx.x;
  const int wave = tid >> 6, lane = tid & 63;
  const int q = lane >> 4, r = lane & 15;

  // ---- stage both weight planes once (coalesced 16B, source pre-XORed)
  {
    const char* gw1 = (const char*)w1h + (long)s * (HID * IN_F * 2);
    const char* gw2 = (const char*)w2h + (long)s * (OUT_F * HID * 2);
#pragma unroll
    for (int it = 0; it < 8; ++it) {   // W1h: 64 KB, 256 B rows
      const int d = it * 8192 + tid * 16;
      const int h = d >> 8, w = d & 255;
      const int src = h * (IN_F * 2) + (w ^ ((h & 7) << 4));
      __builtin_amdgcn_global_load_lds(
          (const __attribute__((address_space(1))) unsigned int*)(gw1 + src),
          (__attribute__((address_space(3))) unsigned int*)(LW1 + d), 16, 0, 0);
    }
#pragma unroll
    for (int it = 0; it < 8; ++it) {   // W2h: 64 KB, 512 B rows
      const int d = it * 8192 + tid * 16;
      const int o = d >> 9, w = d & 511;
      const int src = o * (HID * 2) + (w ^ ((o & 7) << 4));
      __builtin_amdgcn_global_load_lds(
          (const __attribute__((address_space(1))) unsigned int*)(gw2 + src),
          (__attribute__((address_space(3))) unsigned int*)(LW2 + d), 16, 0, 0);
    }
  }

  const int c = sp_cnt[s], base = sp_off[s];
  const int begin = base + (p * c) / 4;
  const int end   = base + ((p + 1) * c) / 4;

  float b2v[8];
#pragma unroll
  for (int ot = 0; ot < 8; ++ot) b2v[ot] = b2g[s * OUT_F + 16 * ot + r];
  const float* b1s = b1g + s * HID;

  char* lxw = smem + 131072 + wave * 4096;
  const int swz = (r & 7) << 4;

  // ---- register prefetch buffer for one atom's raw features (64 VGPR)
  float4 R[16];
  auto ISSUE = [&](int atom) {
    const float* fb = feat + (long)atom * (N_NEIGH * IN_F);
#pragma unroll
    for (int nt = 0; nt < 2; ++nt)
#pragma unroll
      for (int ks = 0; ks < 4; ++ks) {
        const float* ptr = fb + (16 * nt + r) * IN_F + 32 * ks + 8 * q;
        R[nt * 8 + ks * 2]     = *(const float4*)ptr;
        R[nt * 8 + ks * 2 + 1] = *(const float4*)(ptr + 4);
      }
  };

  int idx = begin + wave;
  int a_cur = 0;
  if (idx < end) { a_cur = atom_order[idx]; ISSUE(a_cur); }  // in flight w/ weights

  asm volatile("s_waitcnt vmcnt(0)" ::: "memory");
  __syncthreads();  // the ONLY barrier

  while (idx < end) {
    // ---- split raw features -> bf16 hi/lo frags (consumes R)
    short8 fh[2][4], fl[2][4];
#pragma unroll
    for (int nt = 0; nt < 2; ++nt)
#pragma unroll
      for (int ks = 0; ks < 4; ++ks) {
        float4 v0 = R[nt * 8 + ks * 2];
        float4 v1 = R[nt * 8 + ks * 2 + 1];
        float vv[8] = {v0.x, v0.y, v0.z, v0.w, v1.x, v1.y, v1.z, v1.w};
        short8 h8, l8;
#pragma unroll
        for (int j = 0; j < 8; ++j) {
          HL hl = split2(vv[j]);
          h8[j] = hl.h;
          l8[j] = hl.l;
        }
        fh[nt][ks] = h8;
        fl[nt][ks] = l8;
      }
    const int atom_here = a_cur;
    const int nidx = idx + 8;
    if (nidx < end) { a_cur = atom_order[nidx]; ISSUE(a_cur); }  // prefetch next

    f32x4 oacc[2][8] = {};
    for (int hc = 0; hc < 8; ++hc) {
      // ---- layer 1: x[32 x 32] = feat @ W1h-chunk^T (fh*wh + fl*wh)
      f32x4 xacc[2][2] = {};
#pragma unroll
      for (int ks = 0; ks < 4; ++ks) {
        const int ib = ((32 * ks + 8 * q) * 2) ^ swz;
#pragma unroll
        for (int ht = 0; ht < 2; ++ht) {
          const int row = 32 * hc + 16 * ht + r;         // row&7 == r&7
          short8 bh = *(const short8*)(LW1 + row * 256 + ib);
          xacc[0][ht] = __builtin_amdgcn_mfma_f32_16x16x32_bf16(fh[0][ks], bh, xacc[0][ht], 0, 0, 0);
          xacc[1][ht] = __builtin_amdgcn_mfma_f32_16x16x32_bf16(fh[1][ks], bh, xacc[1][ht], 0, 0, 0);
          xacc[0][ht] = __builtin_amdgcn_mfma_f32_16x16x32_bf16(fl[0][ks], bh, xacc[0][ht], 0, 0, 0);
          xacc[1][ht] = __builtin_amdgcn_mfma_f32_16x16x32_bf16(fl[1][ks], bh, xacc[1][ht], 0, 0, 0);
        }
      }
      // ---- bias + SiLU -> per-wave lx tile (n=16nt+4q+i, h=16ht+r)
#pragma unroll
      for (int ht = 0; ht < 2; ++ht) {
        const float b1v = b1s[hc * 32 + 16 * ht + r];
#pragma unroll
        for (int nt = 0; nt < 2; ++nt)
#pragma unroll
          for (int i = 0; i < 4; ++i) {
            const int n = 16 * nt + 4 * q + i;
            float v = xacc[nt][ht][i] + b1v;
            v = v * __builtin_amdgcn_rcpf(1.0f + __expf(-v));
            const int byte = n * 128 + (((16 * ht + r) * 4) ^ ((n & 7) << 4));
            *(float*)(lxw + byte) = v;
          }
      }
      // ---- read back as layer-2 A-frags (row n=16nt+r, k=8q+j) + split
      short8 ah[2], al[2];
#pragma unroll
      for (int nt = 0; nt < 2; ++nt) {
        const int n = 16 * nt + r;                       // n&7 == r&7
        float4 v0 = *(const float4*)(lxw + n * 128 + ((32 * q) ^ swz));
        float4 v1 = *(const float4*)(lxw + n * 128 + ((32 * q + 16) ^ swz));
        float vv[8] = {v0.x, v0.y, v0.z, v0.w, v1.x, v1.y, v1.z, v1.w};
        short8 h8, l8;
#pragma unroll
        for (int j = 0; j < 8; ++j) {
          HL hl = split2(vv[j]);
          h8[j] = hl.h;
          l8[j] = hl.l;
        }
        ah[nt] = h8;
        al[nt] = l8;
      }
      // ---- layer 2 partial: out += x-chunk @ W2h-chunk^T (ah*wh + al*wh)
      const int kb = ((32 * hc + 8 * q) * 2) ^ swz;
#pragma unroll
      for (int ot = 0; ot < 8; ++ot) {
        const int row = 16 * ot + r;                     // row&7 == r&7
        short8 bw = *(const short8*)(LW2 + row * 512 + kb);
        oacc[0][ot] = __builtin_amdgcn_mfma_f32_16x16x32_bf16(ah[0], bw, oacc[0][ot], 0, 0, 0);
        oacc[1][ot] = __builtin_amdgcn_mfma_f32_16x16x32_bf16(ah[1], bw, oacc[1][ot], 0, 0, 0);
        oacc[0][ot] = __builtin_amdgcn_mfma_f32_16x16x32_bf16(al[0], bw, oacc[0][ot], 0, 0, 0);
        oacc[1][ot] = __builtin_amdgcn_mfma_f32_16x16x32_bf16(al[1], bw, oacc[1][ot], 0, 0, 0);
      }
    }

    // ---- epilogue: bias2 + store this atom
    float* ob = out + (long)atom_here * (N_NEIGH * OUT_F);
#pragma unroll
    for (int ot = 0; ot < 8; ++ot)
#pragma unroll
      for (int nt = 0; nt < 2; ++nt)
#pragma unroll
        for (int i = 0; i < 4; ++i) {
          ob[(16 * nt + 4 * q + i) * OUT_F + 16 * ot + r] = oacc[nt][ot][i] + b2v[ot];
        }

    idx = nidx;
  }
}

extern "C" void kernel_launch(void* const* d_in, const int* in_sizes, int n_in,
                              void* d_out, int out_size, void* d_ws, size_t ws_size,
                              hipStream_t stream) {
  const float* feat = (const float*)d_in[0];
  const int* sp     = (const int*)d_in[1];
  const float* W1   = (const float*)d_in[2];
  const float* b1   = (const float*)d_in[3];
  const float* W2   = (const float*)d_in[4];
  const float* b2   = (const float*)d_in[5];
  float* out = (float*)d_out;

  char* ws = (char*)d_ws;
  unsigned short* w1h = (unsigned short*)(ws + 0);
  unsigned short* w2h = (unsigned short*)(ws + 4194304);
  int* atom_order = (int*)(ws + 8388608);
  int* sp_off     = (int*)(ws + 8388608 + 16384);
  int* sp_cnt     = (int*)(ws + 8388608 + 16384 + 256);

  hipFuncSetAttribute((const void*)mlp_kernel,
                      hipFuncAttributeMaxDynamicSharedMemorySize, 163840);

  hipLaunchKernelGGL(prep_kernel, dim3(1025), dim3(256), 0, stream,
                     W1, W2, sp, w1h, w2h, atom_order, sp_off, sp_cnt);
  hipLaunchKernelGGL(mlp_kernel, dim3(256), dim3(512), 163840, stream,
                     feat, b1, b2, w1h, w2h, atom_order, sp_off, sp_cnt, out);
}

// Round 8
// 181.417 us; speedup vs baseline: 1.0912x; 1.0912x over previous
//
#include <hip/hip_runtime.h>

typedef __attribute__((ext_vector_type(8))) short short8;
typedef __attribute__((ext_vector_type(4))) float f32x4;

#define N_ATOMS 4096
#define N_NEIGH 32
#define IN_F 128
#define HID 256
#define OUT_F 128
#define N_SPECIES 64

// RNE round to bf16 (weights; 2-term split keeps only wh).
__device__ __forceinline__ unsigned short f2bf(float f) {
  unsigned u = __float_as_uint(f);
  u += 0x7FFF + ((u >> 16) & 1);
  return (unsigned short)(u >> 16);
}
// Truncation hi/lo split for activations (hi exact chop, lo exact residual).
struct HL { short h, l; };
__device__ __forceinline__ HL split2(float v) {
  unsigned u = __float_as_uint(v);
  float lo = v - __uint_as_float(u & 0xFFFF0000u);
  HL o;
  o.h = (short)(u >> 16);
  o.l = (short)(__float_as_uint(lo) >> 16);
  return o;
}

// ---------- kernel 1: (block 0) counting sort | (blocks 1..) W -> bf16 RNE ----------
__global__ __launch_bounds__(256) void prep_kernel(
    const float* __restrict__ W1, const float* __restrict__ W2,
    const int* __restrict__ sp_idx,
    unsigned short* __restrict__ w1h, unsigned short* __restrict__ w2h,
    int* __restrict__ atom_order, int* __restrict__ sp_off, int* __restrict__ sp_cnt) {
  const int t = threadIdx.x;
  if (blockIdx.x == 0) {
    __shared__ int cnt[N_SPECIES], off[N_SPECIES], cur[N_SPECIES];
    if (t < N_SPECIES) cnt[t] = 0;
    __syncthreads();
    for (int a = t; a < N_ATOMS; a += 256) atomicAdd(&cnt[sp_idx[a]], 1);
    __syncthreads();
    if (t == 0) {
      int o = 0;
      for (int s = 0; s < N_SPECIES; ++s) { off[s] = o; cur[s] = o; o += cnt[s]; }
    }
    __syncthreads();
    for (int a = t; a < N_ATOMS; a += 256) {
      int s = sp_idx[a];
      atom_order[atomicAdd(&cur[s], 1)] = a;
    }
    if (t < N_SPECIES) { sp_off[t] = off[t]; sp_cnt[t] = cnt[t]; }
    return;
  }
  const int NV = (N_SPECIES * HID * IN_F) / 4;  // float4 count per matrix
  const int nsplit = (gridDim.x - 1) * 256;
  for (int v = (blockIdx.x - 1) * 256 + t; v < 2 * NV; v += nsplit) {
    const float4* src; unsigned short* dh; int j;
    if (v < NV) { src = (const float4*)W1; dh = w1h; j = v; }
    else        { src = (const float4*)W2; dh = w2h; j = v - NV; }
    float4 f = src[j];
    ushort4 h;
    h.x = f2bf(f.x); h.y = f2bf(f.y); h.z = f2bf(f.z); h.w = f2bf(f.w);
    ((ushort4*)dh)[j] = h;
  }
}

// ---------- kernel 2: persistent species-partition MLP, swapped-operand MFMA ----------
// Grid = 256 = (64 species x 4 quarters), 1 block/CU. Stage weights once, one barrier.
// Layer 1 computes x^T = mfma(A=W1, B=feat): lane(q,r) gets x[n=r][h=4q+reg] per tile.
// W1 rows are PERMUTED at staging (pos 16ht+4q+reg <- physical 8q+4ht+reg) so each
// lane's 8 values across (ht,reg) are exactly h = 8q+j -> they ARE the layer-2
// B-fragment after an in-register split+pack. NO per-chunk LDS roundtrip.
// Layer 2: oaccT = mfma(A=W2, B=xh) + mfma(A=W2, B=xl)  (o-major result).
// Epilogue: once per atom, per-wave 4 KB LDS slab transposes o-major -> n-major
// so stores are 128 B contiguous row segments.
// LDS: W1h 64 KB + W2h 64 KB + 8 x 4 KB slab = 160 KB.
__global__ __launch_bounds__(512, 2) void mlp_kernel(
    const float* __restrict__ feat,
    const float* __restrict__ b1g, const float* __restrict__ b2g,
    const unsigned short* __restrict__ w1h, const unsigned short* __restrict__ w2h,
    const int* __restrict__ atom_order, const int* __restrict__ sp_off,
    const int* __restrict__ sp_cnt,
    float* __restrict__ out) {
  extern __shared__ char smem[];
  char* LW1 = smem;            // 64 KB, 256 B rows (position-major, rows permuted)
  char* LW2 = smem + 65536;    // 64 KB, 512 B rows (o-major)

  const int bid = blockIdx.x;
  const int s = (bid & 7) * 8 + (bid >> 5);   // same species -> same XCD slot
  const int p = (bid >> 3) & 3;
  const int tid = threadIdx.x;
  const int wave = tid >> 6, lane = tid & 63;
  const int q = lane >> 4, r = lane & 15;

  // ---- stage both weight planes once (coalesced 16B per lane, source pre-XORed;
  //      W1 additionally row-permuted within each 32-row chunk)
  {
    const char* gw1 = (const char*)w1h + (long)s * (HID * IN_F * 2);
    const char* gw2 = (const char*)w2h + (long)s * (OUT_F * HID * 2);
#pragma unroll
    for (int it = 0; it < 8; ++it) {   // W1h: 64 KB
      const int d = it * 8192 + tid * 16;
      const int pos = d >> 8, wb = d & 255;
      const int pl = pos & 31;                              // position within chunk
      const int hl = ((pl >> 2) & 3) * 8 + ((pl >> 4) & 1) * 4 + (pl & 3);
      const int srow = (pos & ~31) + hl;                    // physical row
      const int src = srow * (IN_F * 2) + (wb ^ ((pos & 7) << 4));
      __builtin_amdgcn_global_load_lds(
          (const __attribute__((address_space(1))) unsigned int*)(gw1 + src),
          (__attribute__((address_space(3))) unsigned int*)(LW1 + d), 16, 0, 0);
    }
#pragma unroll
    for (int it = 0; it < 8; ++it) {   // W2h: 64 KB, 512 B rows
      const int d = it * 8192 + tid * 16;
      const int o = d >> 9, wb = d & 511;
      const int src = o * (HID * 2) + (wb ^ ((o & 7) << 4));
      __builtin_amdgcn_global_load_lds(
          (const __attribute__((address_space(1))) unsigned int*)(gw2 + src),
          (__attribute__((address_space(3))) unsigned int*)(LW2 + d), 16, 0, 0);
    }
  }

  const int c = sp_cnt[s], base = sp_off[s];
  const int begin = base + (p * c) / 4;
  const int end   = base + ((p + 1) * c) / 4;

  const float* b1s = b1g + s * HID;
  const float* b2s = b2g + s * OUT_F;
  char* slab = smem + 131072 + wave * 4096;   // per-wave [32 n][32 o_loc] f32, XOR swz
  const int swz = (r & 7) << 4;

  asm volatile("s_waitcnt vmcnt(0)" ::: "memory");
  __syncthreads();  // the ONLY barrier

  for (int idx = begin + wave; idx < end; idx += 8) {
    const int atom = atom_order[idx];

    // ---- features -> bf16 hi/lo B-frags: lane holds feat[n=16nt+r][i=32ks+8q+j]
    short8 fh[2][4], fl[2][4];
    {
      const float* fb = feat + (long)atom * (N_NEIGH * IN_F);
#pragma unroll
      for (int nt = 0; nt < 2; ++nt)
#pragma unroll
        for (int ks = 0; ks < 4; ++ks) {
          const float* ptr = fb + (16 * nt + r) * IN_F + 32 * ks + 8 * q;
          float4 v0 = *(const float4*)ptr;
          float4 v1 = *(const float4*)(ptr + 4);
          float vv[8] = {v0.x, v0.y, v0.z, v0.w, v1.x, v1.y, v1.z, v1.w};
          short8 h8, l8;
#pragma unroll
          for (int j = 0; j < 8; ++j) {
            HL hl = split2(vv[j]);
            h8[j] = hl.h;
            l8[j] = hl.l;
          }
          fh[nt][ks] = h8;
          fl[nt][ks] = l8;
        }
    }

    f32x4 oacc[8][2] = {};   // [ot][nt]: lane(q,r) holds out^T[o=16ot+4q+reg][n=16nt+r]

    for (int hc = 0; hc < 8; ++hc) {
      // ---- layer 1 swapped: xT[ht][nt] = sum_ks mfma(A=W1pos, B=feat)
      f32x4 xacc[2][2] = {};
#pragma unroll
      for (int ks = 0; ks < 4; ++ks) {
        const int ib = ((32 * ks + 8 * q) * 2) ^ swz;
#pragma unroll
        for (int ht = 0; ht < 2; ++ht) {
          const int pos = 32 * hc + 16 * ht + r;           // pos&7 == r&7
          short8 aw = *(const short8*)(LW1 + pos * 256 + ib);
          xacc[ht][0] = __builtin_amdgcn_mfma_f32_16x16x32_bf16(aw, fh[0][ks], xacc[ht][0], 0, 0, 0);
          xacc[ht][1] = __builtin_amdgcn_mfma_f32_16x16x32_bf16(aw, fh[1][ks], xacc[ht][1], 0, 0, 0);
          xacc[ht][0] = __builtin_amdgcn_mfma_f32_16x16x32_bf16(aw, fl[0][ks], xacc[ht][0], 0, 0, 0);
          xacc[ht][1] = __builtin_amdgcn_mfma_f32_16x16x32_bf16(aw, fl[1][ks], xacc[ht][1], 0, 0, 0);
        }
      }
      // ---- bias + SiLU + split + pack IN REGISTERS: lane's h = 8q + (4ht+reg)
      short8 xh[2], xl[2];
#pragma unroll
      for (int ht = 0; ht < 2; ++ht) {
        const float4 b1c = *(const float4*)(b1s + hc * 32 + 8 * q + 4 * ht);
        const float bb[4] = {b1c.x, b1c.y, b1c.z, b1c.w};
#pragma unroll
        for (int nt = 0; nt < 2; ++nt)
#pragma unroll
          for (int reg = 0; reg < 4; ++reg) {
            float v = xacc[ht][nt][reg] + bb[reg];
            v = v * __builtin_amdgcn_rcpf(1.0f + __expf(-v));
            HL hl = split2(v);
            xh[nt][4 * ht + reg] = hl.h;
            xl[nt][4 * ht + reg] = hl.l;
          }
      }
      // ---- layer 2 swapped: oaccT += mfma(A=W2, B=xh) + mfma(A=W2, B=xl)
      const int kb = ((32 * hc + 8 * q) * 2) ^ swz;
#pragma unroll
      for (int ot = 0; ot < 8; ++ot) {
        const int row = 16 * ot + r;                        // row&7 == r&7
        short8 aw = *(const short8*)(LW2 + row * 512 + kb);
        oacc[ot][0] = __builtin_amdgcn_mfma_f32_16x16x32_bf16(aw, xh[0], oacc[ot][0], 0, 0, 0);
        oacc[ot][1] = __builtin_amdgcn_mfma_f32_16x16x32_bf16(aw, xh[1], oacc[ot][1], 0, 0, 0);
        oacc[ot][0] = __builtin_amdgcn_mfma_f32_16x16x32_bf16(aw, xl[0], oacc[ot][0], 0, 0, 0);
        oacc[ot][1] = __builtin_amdgcn_mfma_f32_16x16x32_bf16(aw, xl[1], oacc[ot][1], 0, 0, 0);
      }
    }

    // ---- epilogue: per-wave slab transpose (o-major -> n-major), once per atom.
    float* ob = out + (long)atom * (N_NEIGH * OUT_F);
#pragma unroll
    for (int g = 0; g < 4; ++g) {       // 32-o slab: ot = 2g, 2g+1
#pragma unroll
      for (int oh = 0; oh < 2; ++oh) {  // write: b128 at [n=16nt+r][o_loc=16*oh+4q]
        const int ot = 2 * g + oh;
        const float4 b2c = *(const float4*)(b2s + 16 * ot + 4 * q);
        const float bb[4] = {b2c.x, b2c.y, b2c.z, b2c.w};
#pragma unroll
        for (int nt = 0; nt < 2; ++nt) {
          f32x4 v;
#pragma unroll
          for (int reg = 0; reg < 4; ++reg) v[reg] = oacc[ot][nt][reg] + bb[reg];
          const int n = 16 * nt + r;
          const int byte = n * 128 + (((16 * oh + 4 * q) * 4) ^ ((n & 7) << 4));
          *(f32x4*)(slab + byte) = v;
        }
      }
      __builtin_amdgcn_s_waitcnt(0);  // lgkmcnt(0): slab writes visible to this wave
#pragma unroll
      for (int m = 0; m < 4; ++m) {   // read rows n-major, store 128B-contiguous
        const int n = m * 8 + (lane >> 3);
        const int cb = ((lane & 7) * 16) ^ ((n & 7) << 4);
        float4 v = *(const float4*)(slab + n * 128 + cb);
        *(float4*)(ob + n * OUT_F + 32 * g + (lane & 7) * 4) = v;
      }
      __builtin_amdgcn_s_waitcnt(0);  // drain before overwriting slab next g
    }
  }
}

extern "C" void kernel_launch(void* const* d_in, const int* in_sizes, int n_in,
                              void* d_out, int out_size, void* d_ws, size_t ws_size,
                              hipStream_t stream) {
  const float* feat = (const float*)d_in[0];
  const int* sp     = (const int*)d_in[1];
  const float* W1   = (const float*)d_in[2];
  const float* b1   = (const float*)d_in[3];
  const float* W2   = (const float*)d_in[4];
  const float* b2   = (const float*)d_in[5];
  float* out = (float*)d_out;

  char* ws = (char*)d_ws;
  unsigned short* w1h = (unsigned short*)(ws + 0);
  unsigned short* w2h = (unsigned short*)(ws + 4194304);
  int* atom_order = (int*)(ws + 8388608);
  int* sp_off     = (int*)(ws + 8388608 + 16384);
  int* sp_cnt     = (int*)(ws + 8388608 + 16384 + 256);

  hipFuncSetAttribute((const void*)mlp_kernel,
                      hipFuncAttributeMaxDynamicSharedMemorySize, 163840);

  hipLaunchKernelGGL(prep_kernel, dim3(1025), dim3(256), 0, stream,
                     W1, W2, sp, w1h, w2h, atom_order, sp_off, sp_cnt);
  hipLaunchKernelGGL(mlp_kernel, dim3(256), dim3(512), 163840, stream,
                     feat, b1, b2, w1h, w2h, atom_order, sp_off, sp_cnt, out);
}